// Round 13
// baseline (703.744 us; speedup 1.0000x reference)
//
#include <hip/hip_runtime.h>
#include <hip/hip_bf16.h>

#define SEQ 2048
#define BATCH 16
#define HID 512
#define OUT_DIM 10
#define NLAYERS 5
#define M_ROWS (SEQ * BATCH)   // 32768
#define N3H (3 * HID)          // 1536
#define GK HID                 // GEMM K

#define CHUNK 32
#define NSEG (SEQ / CHUNK)     // 64

typedef __attribute__((ext_vector_type(8))) _Float16 f16x8;
typedef __attribute__((ext_vector_type(4))) float f32x4;
typedef __attribute__((ext_vector_type(8))) unsigned short u16x8;

__device__ __forceinline__ unsigned short f2h(float x) {
  return __builtin_bit_cast(unsigned short, (_Float16)x);
}
__device__ __forceinline__ float h2f(unsigned short v) {
  return (float)__builtin_bit_cast(_Float16, v);
}
__device__ __forceinline__ float sigm(float x) { return 1.f / (1.f + __expf(-x)); }

// ---------------- f32 -> f16 bulk convert (8 elems/thread) ----------------
__global__ __launch_bounds__(256) void cvt_f32_to_f16(const float* __restrict__ in,
                                                      unsigned short* __restrict__ out) {
  size_t i = ((size_t)blockIdx.x * 256 + threadIdx.x) * 8;
  float4 a = *(const float4*)(in + i);
  float4 b = *(const float4*)(in + i + 4);
  u16x8 r;
  r[0] = f2h(a.x); r[1] = f2h(a.y); r[2] = f2h(a.z); r[3] = f2h(a.w);
  r[4] = f2h(b.x); r[5] = f2h(b.y); r[6] = f2h(b.z); r[7] = f2h(b.w);
  *(u16x8*)(out + i) = r;
}

// ---------------- f16 MFMA GEMM + fused gate epilogue ----------------
// C[m][n] = sum_k A[m][k] * B[n][k]. A:[M][512], B:[1536][512] (B^T).
// Epilogue: for gated column-panels (bn >= 4, i.e. the zf/zr sections) apply
// sigmoid(acc + bias[col-512]) in f32 BEFORE the f16 store — U becomes
// [xt | f | r] and the scan needs no transcendentals and no f/x retention
// (f16 f is stored once -> phase1/phase3 consistency by construction).
// Note: for BOTH sections the bias index is col-512 (bf at [h], br at [512+h]).
__global__ __launch_bounds__(256) void gemm_mfma(const unsigned short* __restrict__ A,
                                                 const unsigned short* __restrict__ B,
                                                 const float* __restrict__ bias,  // [1024]
                                                 unsigned short* __restrict__ C) {
  __shared__ unsigned short lds[3][8192];
  const int tid = threadIdx.x;
  const int nwg = (M_ROWS / 128) * (N3H / 128);      // 3072
  const int cpx = nwg / 8;                           // 384 (bijective: 3072 % 8 == 0)
  const int swz = (blockIdx.x % 8) * cpx + blockIdx.x / 8;
  const int bm = swz / (N3H / 128);
  const int bn = swz % (N3H / 128);
  const int lane = tid & 63;
  const int wid = tid >> 6;
  const int wm = (wid >> 1) * 64, wn = (wid & 1) * 64;

  const unsigned short* Ag = A + (size_t)bm * 128 * GK;
  const unsigned short* Bg = B + (size_t)bn * 128 * GK;

  const int s0 = tid, s1 = tid + 256;
  const int r0 = s0 >> 2, c0 = (s0 & 3) * 8;
  const int r1 = s1 >> 2, c1 = (s1 & 3) * 8;

  const int fr = lane & 15;         // fragment row (M for A, N for B)
  const int ko = (lane >> 4) * 8;   // fragment k offset (8 contiguous)

  f32x4 acc[4][4];
#pragma unroll
  for (int i = 0; i < 4; ++i)
#pragma unroll
    for (int j = 0; j < 4; ++j) acc[i][j] = (f32x4){0.f, 0.f, 0.f, 0.f};

#define STAGE(buf, k0)                                                                              \
  {                                                                                                 \
    __builtin_amdgcn_global_load_lds(                                                               \
        (const __attribute__((address_space(1))) void*)(Ag + (size_t)r0 * GK + (k0) + c0),          \
        (__attribute__((address_space(3))) void*)&lds[buf][s0 * 8], 16, 0, 0);                      \
    __builtin_amdgcn_global_load_lds(                                                               \
        (const __attribute__((address_space(1))) void*)(Ag + (size_t)r1 * GK + (k0) + c1),          \
        (__attribute__((address_space(3))) void*)&lds[buf][s1 * 8], 16, 0, 0);                      \
    __builtin_amdgcn_global_load_lds(                                                               \
        (const __attribute__((address_space(1))) void*)(Bg + (size_t)r0 * GK + (k0) + c0),          \
        (__attribute__((address_space(3))) void*)&lds[buf][4096 + s0 * 8], 16, 0, 0);               \
    __builtin_amdgcn_global_load_lds(                                                               \
        (const __attribute__((address_space(1))) void*)(Bg + (size_t)r1 * GK + (k0) + c1),          \
        (__attribute__((address_space(3))) void*)&lds[buf][4096 + s1 * 8], 16, 0, 0);               \
  }

  STAGE(0, 0);
  STAGE(1, 32);
#pragma unroll 1
  for (int kt = 0; kt < 16; ++kt) {
    if (kt < 15) {
      asm volatile("s_waitcnt vmcnt(4)" ::: "memory");
    } else {
      asm volatile("s_waitcnt vmcnt(0)" ::: "memory");
    }
    __builtin_amdgcn_s_barrier();
    __builtin_amdgcn_sched_barrier(0);   // pin: nothing moves above the barrier
    if (kt + 2 < 16) STAGE((kt + 2) % 3, (kt + 2) * 32);
    const int cb = kt % 3;
    f16x8 af[4], bfr[4];
#pragma unroll
    for (int t = 0; t < 4; ++t) {
      af[t]  = *(const f16x8*)&lds[cb][(wm + t * 16 + fr) * 32 + ko];
      bfr[t] = *(const f16x8*)&lds[cb][4096 + (wn + t * 16 + fr) * 32 + ko];
    }
#pragma unroll
    for (int mt = 0; mt < 4; ++mt)
#pragma unroll
      for (int nt = 0; nt < 4; ++nt)
        acc[mt][nt] = __builtin_amdgcn_mfma_f32_16x16x32_f16(af[mt], bfr[nt], acc[mt][nt], 0, 0, 0);
  }
#undef STAGE

  // ---- epilogue: optional gate, then coalesced C-write via LDS transpose ----
  __syncthreads();  // all waves done reading buffers
  unsigned short* cl = &lds[0][0];
  const int er = (lane >> 4) * 4;   // C/D layout: col=lane&15, row=(lane>>4)*4+reg
  const bool gated = (bn >= 4);     // whole 128-col panel inside zf/zr sections
#pragma unroll
  for (int mt = 0; mt < 4; ++mt)
#pragma unroll
    for (int nt = 0; nt < 4; ++nt) {
      const int row = wm + mt * 16 + er;
      const int col = wn + nt * 16 + fr;
      const float bv = gated ? bias[bn * 128 + col - 512] : 0.f;
#pragma unroll
      for (int j = 0; j < 4; ++j) {
        float v = acc[mt][nt][j];
        if (gated) v = sigm(v + bv);
        cl[(row + j) * 136 + col] = f2h(v);
      }
    }
  __syncthreads();
  unsigned short* Cb = C + (size_t)bm * 128 * N3H + bn * 128;
#pragma unroll
  for (int i = 0; i < 8; ++i) {
    int flat = i * 2048 + tid * 8;
    int r = flat >> 7, c = flat & 127;
    *(u16x8*)(Cb + (size_t)r * N3H + c) = *(const u16x8*)&cl[r * 136 + c];
  }
}

// ---------------- Fused single-pass SRU scan (decoupled lookback, 8h/thread) ----------------
// One wave per (segment, batch) pair; 4 pairs per 256-thr block; 256 blocks
// (trivially all-resident on 256 CUs; publish-before-wait => no deadlock).
// U = [xt | f | r] with f,r PRE-GATED f16 (from the GEMM epilogue) -> no
// transcendentals here, and phase1/phase3 read the identical stored f.
// All loads/stores u16x8 = 16B/lane = 1024B/wave (coalescing sweet spot).
// Publish (F, C) packed in ONE 64-bit word via atomicExch; F stored NEGATED
// so the low word's sign bit doubles as the "published" tag. FC pre-zeroed.
__global__ __launch_bounds__(256) void sru_scan_fused(
    const unsigned short* __restrict__ U,     // [L][B][3H] f16: xt | f | r
    unsigned long long* __restrict__ FC,      // [NSEG][B][H] packed, pre-zeroed
    unsigned short* hb) {                     // [L][B][H] f16, updated in place
  const int wid = threadIdx.x >> 6;
  const int lane = threadIdx.x & 63;
  const int p = blockIdx.x * 4 + wid;  // pair id 0..1023
  const int s = p >> 4;
  const int b = p & 15;
  const int h0 = lane * 8;

  const size_t rowstep = (size_t)BATCH * N3H;
  const unsigned short* Up = U + ((size_t)(s * CHUNK) * BATCH + b) * N3H + h0;

  // ---- phase 1: local (F, C | c0=0)
  float F[8], c[8];
#pragma unroll
  for (int j = 0; j < 8; ++j) { F[j] = 1.f; c[j] = 0.f; }
#pragma unroll 4
  for (int i = 0; i < CHUNK; ++i) {
    const unsigned short* up = Up + (size_t)i * rowstep;
    u16x8 xt = *(const u16x8*)(up);
    u16x8 fv = *(const u16x8*)(up + HID);
#pragma unroll
    for (int j = 0; j < 8; ++j) {
      float f = h2f(fv[j]);
      c[j] = f * c[j] + (1.f - f) * h2f(xt[j]);
      F[j] *= f;
    }
  }

  // ---- publish (single-word atomics; no fence needed)
  const size_t ch = ((size_t)s * BATCH + b) * HID + h0;
#pragma unroll
  for (int j = 0; j < 8; ++j)
    atomicExch(&FC[ch + j],
               ((unsigned long long)__builtin_bit_cast(unsigned, c[j]) << 32) |
                   __builtin_bit_cast(unsigned, -F[j]));

  // ---- lookback: c_in = sum_{j<s} C_j * prod_{j<k<s} F_k
  float ci[8], P[8];
#pragma unroll
  for (int j = 0; j < 8; ++j) { ci[j] = 0.f; P[j] = 1.f; }
  for (int jj = s - 1; jj >= 0; --jj) {
    const size_t cj = ((size_t)jj * BATCH + b) * HID + h0;
    unsigned long long v[8];
#pragma unroll
    for (int j = 0; j < 8; ++j) v[j] = atomicAdd(&FC[cj + j], 0ULL);  // batch-issue
    bool all;
    do {
      all = true;
#pragma unroll
      for (int j = 0; j < 8; ++j)
        if (!(v[j] & 0x80000000ULL)) { v[j] = atomicAdd(&FC[cj + j], 0ULL); all = false; }
    } while (!all);
    float pm = 0.f;
#pragma unroll
    for (int j = 0; j < 8; ++j) {
      float Fj = -__builtin_bit_cast(float, (unsigned)v[j]);
      float Cj = __builtin_bit_cast(float, (unsigned)(v[j] >> 32));
      ci[j] += P[j] * Cj;
      P[j] *= Fj;
      pm = fmaxf(pm, P[j]);
    }
    if (pm < 1e-5f) break;   // remaining contribution < f16 ulp
  }

  // ---- phase 3: replay with carry; h written in place (thread owns its 16B)
  const size_t hstep = (size_t)BATCH * HID;
  unsigned short* hp = hb + ((size_t)(s * CHUNK) * BATCH + b) * HID + h0;
#pragma unroll 4
  for (int i = 0; i < CHUNK; ++i) {
    const unsigned short* up = Up + (size_t)i * rowstep;
    u16x8 xt = *(const u16x8*)(up);
    u16x8 fv = *(const u16x8*)(up + HID);
    u16x8 rv = *(const u16x8*)(up + 2 * HID);
    u16x8 hv = *(const u16x8*)(hp + (size_t)i * hstep);
    u16x8 ho;
#pragma unroll
    for (int j = 0; j < 8; ++j) {
      float f = h2f(fv[j]);
      float r = h2f(rv[j]);
      ci[j] = f * ci[j] + (1.f - f) * h2f(xt[j]);
      ho[j] = f2h(r * ci[j] + (1.f - r) * h2f(hv[j]));
    }
    *(u16x8*)(hp + (size_t)i * hstep) = ho;
  }
}

// ---------------- FC head (f16 H, f32 math) ----------------
#define FCR 16
__global__ __launch_bounds__(256) void fc_kernel(const unsigned short* __restrict__ H,
                                                 const float* __restrict__ W,
                                                 const float* __restrict__ bv,
                                                 float* __restrict__ out) {
  __shared__ float hs[FCR][516];
  __shared__ float ws[OUT_DIM][516];
  const int tid = threadIdx.x;
  const size_t m0 = (size_t)blockIdx.x * FCR;
#pragma unroll
  for (int i = 0; i < 4; ++i) {
    int f = tid + i * 256;
    int row = f >> 6;     // 0..15
    int kq = f & 63;      // 8-elem group
    u16x8 v = *(const u16x8*)(H + (m0 + row) * 512 + kq * 8);
#pragma unroll
    for (int j = 0; j < 8; ++j) hs[row][kq * 8 + j] = h2f(v[j]);
  }
#pragma unroll
  for (int i = 0; i < 5; ++i) {
    int f = tid + i * 256;
    int row = f >> 7;     // 0..9
    int kq = f & 127;
    float4 v = *(const float4*)(W + row * 512 + kq * 4);
    *(float4*)&ws[row][kq * 4] = v;
  }
  __syncthreads();
  if (tid < FCR * OUT_DIM) {
    int row = tid / OUT_DIM;
    int o = tid - row * OUT_DIM;
    float acc = bv[o];
#pragma unroll 8
    for (int k = 0; k < 512; ++k) acc += hs[row][k] * ws[o][k];
    out[(m0 + row) * OUT_DIM + o] = acc;
  }
}

extern "C" void kernel_launch(void* const* d_in, const int* in_sizes, int n_in,
                              void* d_out, int out_size, void* d_ws, size_t ws_size,
                              hipStream_t stream) {
  const float* x   = (const float*)d_in[0];  // [2048][16][512]
  const float* Ws  = (const float*)d_in[1];  // [5][1536][512]
  const float* bs  = (const float*)d_in[2];  // [5][1024]
  const float* fcW = (const float*)d_in[3];  // [10][512]
  const float* fcb = (const float*)d_in[4];  // [10]
  float* out = (float*)d_out;

  char* ws = (char*)d_ws;
  const size_t MiB = 1024 * 1024;
  unsigned short* Ub = (unsigned short*)ws;                  // 96 MiB: [M][1536] f16
  unsigned short* hb = (unsigned short*)(ws + 96 * MiB);     // 32 MiB: [M][512] f16
  unsigned short* Wh = (unsigned short*)(ws + 128 * MiB);    // 7.5 MiB f16 weights
  unsigned long long* FC = (unsigned long long*)(ws + 136 * MiB);  // 20 MiB: 5 epochs
  // total 156 MiB <= 256 MiB workspace

  // one-time converts + single lookback-buffer clear for ALL layers
  hipMemsetAsync(FC, 0, (size_t)NLAYERS * NSEG * BATCH * HID * 8, stream);
  cvt_f32_to_f16<<<(NLAYERS * N3H * HID) / (256 * 8), 256, 0, stream>>>(Ws, Wh);
  cvt_f32_to_f16<<<(M_ROWS * HID) / (256 * 8), 256, 0, stream>>>(x, hb);

  for (int l = 0; l < NLAYERS; ++l) {
    gemm_mfma<<<(M_ROWS / 128) * (N3H / 128), 256, 0, stream>>>(
        hb, Wh + (size_t)l * N3H * HID, bs + (size_t)l * 2 * HID, Ub);
    sru_scan_fused<<<NSEG * BATCH / 4, 256, 0, stream>>>(
        Ub, FC + (size_t)l * NSEG * BATCH * HID, hb);
  }
  fc_kernel<<<M_ROWS / FCR, 256, 0, stream>>>(hb, fcW, fcb, out);
}

// Round 14
// 632.960 us; speedup vs baseline: 1.1118x; 1.1118x over previous
//
#include <hip/hip_runtime.h>
#include <hip/hip_bf16.h>

#define SEQ 2048
#define BATCH 16
#define HID 512
#define OUT_DIM 10
#define NLAYERS 5
#define M_ROWS (SEQ * BATCH)   // 32768
#define N3H (3 * HID)          // 1536
#define GK HID                 // GEMM K

#define CHUNK 32
#define NSEG (SEQ / CHUNK)     // 64

typedef __attribute__((ext_vector_type(8))) _Float16 f16x8;
typedef __attribute__((ext_vector_type(4))) float f32x4;
typedef __attribute__((ext_vector_type(8))) unsigned short u16x8;

__device__ __forceinline__ unsigned short f2h(float x) {
  return __builtin_bit_cast(unsigned short, (_Float16)x);
}
__device__ __forceinline__ float h2f(unsigned short v) {
  return (float)__builtin_bit_cast(_Float16, v);
}
__device__ __forceinline__ float sigm(float x) { return 1.f / (1.f + __expf(-x)); }

// ---------------- f32 -> f16 bulk convert (8 elems/thread) ----------------
__global__ __launch_bounds__(256) void cvt_f32_to_f16(const float* __restrict__ in,
                                                      unsigned short* __restrict__ out) {
  size_t i = ((size_t)blockIdx.x * 256 + threadIdx.x) * 8;
  float4 a = *(const float4*)(in + i);
  float4 b = *(const float4*)(in + i + 4);
  u16x8 r;
  r[0] = f2h(a.x); r[1] = f2h(a.y); r[2] = f2h(a.z); r[3] = f2h(a.w);
  r[4] = f2h(b.x); r[5] = f2h(b.y); r[6] = f2h(b.z); r[7] = f2h(b.w);
  *(u16x8*)(out + i) = r;
}

// ---------------- 8-phase 256x256 f16 MFMA GEMM (T3+T4+T5 template) ----------------
// C[m][n] = sum_k A[m][k] * B[n][k]. A:[M][512], B:[1536][512] (B^T), C:[M][1536] f16.
// 512 thr = 8 waves (2Mx4N), per-wave C = 128x64 (8x4 frags of 16x16).
// K = 512 = 8 K-tiles of BK=64; each tile = 2 kc-halves of 32k. LDS holds
// 2 tiles x 2 kc x (A 256x32 + B 256x32) = 128 KB (double-buffer by tile parity).
// Phase p of iter t (tiles 2t, 2t+1): computes (tile = 2t+(p>4), kc = ((p-1)>>1)&1,
// m-group = (p-1)&1), 16 MFMA; stages ONE operand-half S_{8t+p+5} into the slot
// freed two phases earlier (safe: prior closing barrier + compiler lgkmcnt).
// Half-stage order: S_{4m}=Tm.k0.A, +1=.B, +2=Tm.k1.A, +3=.B. Counted waits:
// vmcnt(8) before every even phase's closing barrier retires exactly through the
// half needed 2 phases later (FIFO ledger verified for all 32 stages); last iter
// tail: P4 -> vmcnt(4), P6 -> vmcnt(0). sched_barrier(0) after every s_barrier
// pins hoisting; setprio(1) wraps the MFMA cluster (T5).
__global__ __launch_bounds__(512, 1) void gemm_8ph(const unsigned short* __restrict__ A,
                                                   const unsigned short* __restrict__ B,
                                                   unsigned short* __restrict__ C) {
  // staging: A planes [4][256][32] f16 at 0, B planes at 32768 (elem offsets);
  // epilogue reuses as 256x264 C-transpose (67584 f16 = 132 KB).
  __shared__ __align__(16) unsigned short lds[67584];
  const int tid = threadIdx.x;
  const int nwg = (M_ROWS / 256) * (N3H / 256);      // 128*6 = 768
  const int cpx = nwg / 8;                           // 96 (bijective: 768 % 8 == 0)
  const int swz = (blockIdx.x % 8) * cpx + blockIdx.x / 8;
  const int bm = swz / (N3H / 256);
  const int bn = swz % (N3H / 256);
  const int lane = tid & 63;
  const int wid = tid >> 6;        // 0..7
  const int wr = wid >> 2;         // 0..1  (M half)
  const int wc = wid & 3;          // 0..3  (N quarter)
  const int fr = lane & 15;        // fragment row
  const int koq = lane >> 4;       // k slot (0..3, 8 f16 each)

  const unsigned short* Ag = A + (size_t)bm * 256 * GK;
  const unsigned short* Bg = B + (size_t)bn * 256 * GK;

  // staging geometry: one operand-half = 256 rows x 32 k = 16 KB; wave w covers
  // rows [w*32, w*32+32) via 2 instrs (16 rows x 1 KB each); lane l -> row
  // w*32 + jj*16 + (l>>2), k8 = (l&3)*8. LDS dest linear: plane + w*1024 +
  // jj*512 + l*8 elems (lane0 value = wave-uniform base, HW adds lane*16B).
  const int srow = wid * 32 + (lane >> 2);
  const int sk8 = (lane & 3) * 8;

#define ISSUE_STAGE(j)                                                                              \
  if ((j) < 32) {                                                                                   \
    const int Ts = (j) >> 2, kcs = ((j) >> 1) & 1, isB = (j) & 1;                                   \
    const unsigned short* gsrc = isB ? Bg : Ag;                                                     \
    const int kb = Ts * 64 + kcs * 32;                                                              \
    const int pl = (isB ? 32768 : 0) + (((Ts & 1) * 2 + kcs) << 13);                                \
    __builtin_amdgcn_global_load_lds(                                                               \
        (const __attribute__((address_space(1))) void*)(gsrc + (size_t)srow * GK + kb + sk8),       \
        (__attribute__((address_space(3))) void*)&lds[pl + wid * 1024 + lane * 8], 16, 0, 0);       \
    __builtin_amdgcn_global_load_lds(                                                               \
        (const __attribute__((address_space(1))) void*)(gsrc + (size_t)(srow + 16) * GK + kb + sk8),\
        (__attribute__((address_space(3))) void*)&lds[pl + wid * 1024 + 512 + lane * 8], 16, 0, 0); \
  }

  f32x4 acc[8][4];
#pragma unroll
  for (int i = 0; i < 8; ++i)
#pragma unroll
    for (int j = 0; j < 4; ++j) acc[i][j] = (f32x4){0.f, 0.f, 0.f, 0.f};

  f16x8 bfr[4];  // B-frags persist across the (mg=0, mg=1) phase pair

#define PHASE(p, t)                                                                                 \
  {                                                                                                 \
    constexpr int par = ((p) > 4) ? 1 : 0;                                                          \
    constexpr int kc = (((p)-1) >> 1) & 1;                                                          \
    constexpr int mg = ((p)-1) & 1;                                                                 \
    constexpr int apl = (par * 2 + kc) << 13;                                                       \
    constexpr int bpl = 32768 + ((par * 2 + kc) << 13);                                             \
    f16x8 af[4];                                                                                    \
    _Pragma("unroll") for (int m2 = 0; m2 < 4; ++m2)                                                \
        af[m2] = *(const f16x8*)&lds[apl + (wr * 128 + (mg * 4 + m2) * 16 + fr) * 32 + koq * 8];    \
    if (mg == 0) {                                                                                  \
      _Pragma("unroll") for (int n2 = 0; n2 < 4; ++n2)                                              \
          bfr[n2] = *(const f16x8*)&lds[bpl + (wc * 64 + n2 * 16 + fr) * 32 + koq * 8];             \
    }                                                                                               \
    ISSUE_STAGE(8 * (t) + (p) + 5);                                                                 \
    __builtin_amdgcn_s_barrier();                                                                   \
    __builtin_amdgcn_sched_barrier(0);                                                              \
    __builtin_amdgcn_s_setprio(1);                                                                  \
    _Pragma("unroll") for (int m2 = 0; m2 < 4; ++m2)                                                \
      _Pragma("unroll") for (int n2 = 0; n2 < 4; ++n2)                                              \
        acc[mg * 4 + m2][n2] =                                                                      \
            __builtin_amdgcn_mfma_f32_16x16x32_f16(af[m2], bfr[n2], acc[mg * 4 + m2][n2], 0, 0, 0); \
    __builtin_amdgcn_s_setprio(0);                                                                  \
    if ((p) % 2 == 0) {                                                                             \
      if ((t) < 3) {                                                                                \
        asm volatile("s_waitcnt vmcnt(8)" ::: "memory");                                            \
      } else if ((p) == 2) {                                                                        \
        asm volatile("s_waitcnt vmcnt(8)" ::: "memory");                                            \
      } else if ((p) == 4) {                                                                        \
        asm volatile("s_waitcnt vmcnt(4)" ::: "memory");                                            \
      } else if ((p) == 6) {                                                                        \
        asm volatile("s_waitcnt vmcnt(0)" ::: "memory");                                            \
      }                                                                                             \
    }                                                                                               \
    __builtin_amdgcn_s_barrier();                                                                   \
    __builtin_amdgcn_sched_barrier(0);                                                              \
  }

  // prologue: stage S0..S5 (T0.k0 A,B; T0.k1 A,B; T1.k0 A,B); T0.k0 ready at vmcnt(8)
#pragma unroll
  for (int js = 0; js < 6; ++js) ISSUE_STAGE(js);
  asm volatile("s_waitcnt vmcnt(8)" ::: "memory");
  __builtin_amdgcn_s_barrier();
  __builtin_amdgcn_sched_barrier(0);

#pragma unroll 1
  for (int t = 0; t < 4; ++t) {
    PHASE(1, t) PHASE(2, t) PHASE(3, t) PHASE(4, t)
    PHASE(5, t) PHASE(6, t) PHASE(7, t) PHASE(8, t)
  }
#undef PHASE
#undef ISSUE_STAGE

  // ---- epilogue: coalesced C-write via LDS transpose (256 x 264-pad) ----
  __syncthreads();   // all reads done (last closing barrier) + full drain
  const int er = (lane >> 4) * 4;   // C/D layout: col=lane&15, row=(lane>>4)*4+reg
#pragma unroll
  for (int mf = 0; mf < 8; ++mf)
#pragma unroll
    for (int nf = 0; nf < 4; ++nf) {
      const int row = wr * 128 + mf * 16 + er;
      const int col = wc * 64 + nf * 16 + fr;
#pragma unroll
      for (int j = 0; j < 4; ++j) lds[(row + j) * 264 + col] = f2h(acc[mf][nf][j]);
    }
  __syncthreads();
  unsigned short* Cb = C + (size_t)bm * 256 * N3H + bn * 256;
#pragma unroll
  for (int i = 0; i < 16; ++i) {
    int flat = i * 4096 + tid * 8;
    int r = flat >> 8, c = flat & 255;
    *(u16x8*)(Cb + (size_t)r * N3H + c) = *(const u16x8*)&lds[r * 264 + c];
  }
}

// ---------------- Fused single-pass SRU scan (decoupled lookback) ----------------
// Grid: 64 segments x 16 batch = 1024 blocks; 256 thr x 2h = 512 chains/block.
// Publish (F, C) packed in ONE 64-bit word via atomicExch; F stored NEGATED so
// the low word's sign bit doubles as the "published" tag. FC pre-zeroed (one
// memset covers all 5 layer epochs). Lookback early-exit at P < 1e-5.
__global__ __launch_bounds__(256, 4) void sru_scan_fused(
    const unsigned short* __restrict__ U,     // [L][B][3H] f16: xt | zf | zr
    const float* __restrict__ bias,           // [2H]
    unsigned long long* __restrict__ FC,      // [NSEG][B][H] packed, pre-zeroed
    unsigned short* hb) {                     // [L][B][H] f16, updated in place
  const int s = blockIdx.x >> 4;
  const int b = blockIdx.x & 15;
  const int h0 = threadIdx.x << 1;
  const float bf0 = bias[h0], bf1 = bias[h0 + 1];
  const float br0 = bias[HID + h0], br1 = bias[HID + h0 + 1];

  const size_t rowstep = (size_t)BATCH * N3H;
  const unsigned short* Up = U + ((size_t)(s * CHUNK) * BATCH + b) * N3H + h0;

  // ---- phase 1: local (F, C | c0=0); retain packed (f16 f, f16 xt) per step
  unsigned fx0[CHUNK], fx1[CHUNK];
  float F0 = 1.f, F1 = 1.f, c0 = 0.f, c1 = 0.f;
#pragma unroll
  for (int i = 0; i < CHUNK; ++i) {
    const unsigned short* p = Up + (size_t)i * rowstep;
    unsigned xt = *(const unsigned*)(p);
    unsigned zf = *(const unsigned*)(p + HID);
    unsigned short fh0 = f2h(sigm(h2f((unsigned short)zf) + bf0));
    unsigned short fh1 = f2h(sigm(h2f((unsigned short)(zf >> 16)) + bf1));
    float f0 = h2f(fh0), f1 = h2f(fh1);
    c0 = f0 * c0 + (1.f - f0) * h2f((unsigned short)xt);
    c1 = f1 * c1 + (1.f - f1) * h2f((unsigned short)(xt >> 16));
    F0 *= f0; F1 *= f1;
    fx0[i] = (xt & 0xffffu) | ((unsigned)fh0 << 16);
    fx1[i] = (xt >> 16) | ((unsigned)fh1 << 16);
  }

  // ---- publish (single-word atomic; no fence needed)
  const size_t ch = ((size_t)s * BATCH + b) * HID + h0;
  atomicExch(&FC[ch],
             ((unsigned long long)__builtin_bit_cast(unsigned, c0) << 32) |
                 __builtin_bit_cast(unsigned, -F0));
  atomicExch(&FC[ch + 1],
             ((unsigned long long)__builtin_bit_cast(unsigned, c1) << 32) |
                 __builtin_bit_cast(unsigned, -F1));

  // ---- lookback: c_in = sum_{j<s} C_j * prod_{j<k<s} F_k
  float ci0 = 0.f, ci1 = 0.f, P0 = 1.f, P1 = 1.f;
  for (int j = s - 1; j >= 0; --j) {
    const size_t cj = ((size_t)j * BATCH + b) * HID + h0;
    unsigned long long v0, v1;
    do { v0 = atomicAdd(&FC[cj], 0ULL); } while (!(v0 & 0x80000000ULL));
    do { v1 = atomicAdd(&FC[cj + 1], 0ULL); } while (!(v1 & 0x80000000ULL));
    float Fj0 = -__builtin_bit_cast(float, (unsigned)v0);
    float Cj0 = __builtin_bit_cast(float, (unsigned)(v0 >> 32));
    float Fj1 = -__builtin_bit_cast(float, (unsigned)v1);
    float Cj1 = __builtin_bit_cast(float, (unsigned)(v1 >> 32));
    ci0 += P0 * Cj0; P0 *= Fj0;
    ci1 += P1 * Cj1; P1 *= Fj1;
    if (P0 < 1e-5f && P1 < 1e-5f) break;   // remaining contribution < f16 ulp
  }

  // ---- phase 3: replay with carry; read zr + x, write h in place
  float cc0 = ci0, cc1 = ci1;
  const size_t hstep = (size_t)BATCH * HID;
  unsigned short* hp = hb + ((size_t)(s * CHUNK) * BATCH + b) * HID + h0;
#pragma unroll
  for (int i = 0; i < CHUNK; ++i) {
    unsigned zr = *(const unsigned*)(Up + (size_t)i * rowstep + 2 * HID);
    unsigned xv = *(const unsigned*)(hp + (size_t)i * hstep);
    float f0 = h2f((unsigned short)(fx0[i] >> 16));
    float f1 = h2f((unsigned short)(fx1[i] >> 16));
    cc0 = f0 * cc0 + (1.f - f0) * h2f((unsigned short)fx0[i]);
    cc1 = f1 * cc1 + (1.f - f1) * h2f((unsigned short)fx1[i]);
    float r0 = sigm(h2f((unsigned short)zr) + br0);
    float r1 = sigm(h2f((unsigned short)(zr >> 16)) + br1);
    float hn0 = r0 * cc0 + (1.f - r0) * h2f((unsigned short)xv);
    float hn1 = r1 * cc1 + (1.f - r1) * h2f((unsigned short)(xv >> 16));
    *(unsigned*)(hp + (size_t)i * hstep) = (unsigned)f2h(hn0) | ((unsigned)f2h(hn1) << 16);
  }
}

// ---------------- FC head (f16 H, f32 math) ----------------
#define FCR 16
__global__ __launch_bounds__(256) void fc_kernel(const unsigned short* __restrict__ H,
                                                 const float* __restrict__ W,
                                                 const float* __restrict__ bv,
                                                 float* __restrict__ out) {
  __shared__ float hs[FCR][516];
  __shared__ float ws[OUT_DIM][516];
  const int tid = threadIdx.x;
  const size_t m0 = (size_t)blockIdx.x * FCR;
#pragma unroll
  for (int i = 0; i < 4; ++i) {
    int f = tid + i * 256;
    int row = f >> 6;     // 0..15
    int kq = f & 63;      // 8-elem group
    u16x8 v = *(const u16x8*)(H + (m0 + row) * 512 + kq * 8);
#pragma unroll
    for (int j = 0; j < 8; ++j) hs[row][kq * 8 + j] = h2f(v[j]);
  }
#pragma unroll
  for (int i = 0; i < 5; ++i) {
    int f = tid + i * 256;
    int row = f >> 7;     // 0..9
    int kq = f & 127;
    float4 v = *(const float4*)(W + row * 512 + kq * 4);
    *(float4*)&ws[row][kq * 4] = v;
  }
  __syncthreads();
  if (tid < FCR * OUT_DIM) {
    int row = tid / OUT_DIM;
    int o = tid - row * OUT_DIM;
    float acc = bv[o];
#pragma unroll 8
    for (int k = 0; k < 512; ++k) acc += hs[row][k] * ws[o][k];
    out[(m0 + row) * OUT_DIM + o] = acc;
  }
}

extern "C" void kernel_launch(void* const* d_in, const int* in_sizes, int n_in,
                              void* d_out, int out_size, void* d_ws, size_t ws_size,
                              hipStream_t stream) {
  const float* x   = (const float*)d_in[0];  // [2048][16][512]
  const float* Ws  = (const float*)d_in[1];  // [5][1536][512]
  const float* bs  = (const float*)d_in[2];  // [5][1024]
  const float* fcW = (const float*)d_in[3];  // [10][512]
  const float* fcb = (const float*)d_in[4];  // [10]
  float* out = (float*)d_out;

  char* ws = (char*)d_ws;
  const size_t MiB = 1024 * 1024;
  unsigned short* Ub = (unsigned short*)ws;                  // 96 MiB: [M][1536] f16
  unsigned short* hb = (unsigned short*)(ws + 96 * MiB);     // 32 MiB: [M][512] f16
  unsigned short* Wh = (unsigned short*)(ws + 128 * MiB);    // 7.5 MiB f16 weights
  unsigned long long* FC = (unsigned long long*)(ws + 136 * MiB);  // 20 MiB: 5 epochs
  // total 156 MiB <= 256 MiB workspace

  // one-time converts + single lookback-buffer clear for ALL layers
  hipMemsetAsync(FC, 0, (size_t)NLAYERS * NSEG * BATCH * HID * 8, stream);
  cvt_f32_to_f16<<<(NLAYERS * N3H * HID) / (256 * 8), 256, 0, stream>>>(Ws, Wh);
  cvt_f32_to_f16<<<(M_ROWS * HID) / (256 * 8), 256, 0, stream>>>(x, hb);

  for (int l = 0; l < NLAYERS; ++l) {
    gemm_8ph<<<(M_ROWS / 256) * (N3H / 256), 512, 0, stream>>>(
        hb, Wh + (size_t)l * N3H * HID, Ub);
    sru_scan_fused<<<NSEG * BATCH, 256, 0, stream>>>(
        Ub, bs + (size_t)l * 2 * HID,
        FC + (size_t)l * NSEG * BATCH * HID, hb);
  }
  fc_kernel<<<M_ROWS / FCR, 256, 0, stream>>>(hb, fcW, fcb, out);
}

// Round 15
// 630.359 us; speedup vs baseline: 1.1164x; 1.0041x over previous
//
#include <hip/hip_runtime.h>
#include <hip/hip_bf16.h>

#define SEQ 2048
#define BATCH 16
#define HID 512
#define OUT_DIM 10
#define NLAYERS 5
#define M_ROWS (SEQ * BATCH)   // 32768
#define N3H (3 * HID)          // 1536
#define GK HID                 // GEMM K

#define CHUNK 32
#define NSEG (SEQ / CHUNK)     // 64
#define PREFIX_TAG 0xC0000000u  // bits of -2.0f; aggregates store -F in (-1,-0]

typedef __attribute__((ext_vector_type(8))) _Float16 f16x8;
typedef __attribute__((ext_vector_type(4))) float f32x4;
typedef __attribute__((ext_vector_type(8))) unsigned short u16x8;

__device__ __forceinline__ unsigned short f2h(float x) {
  return __builtin_bit_cast(unsigned short, (_Float16)x);
}
__device__ __forceinline__ float h2f(unsigned short v) {
  return (float)__builtin_bit_cast(_Float16, v);
}
__device__ __forceinline__ float sigm(float x) { return 1.f / (1.f + __expf(-x)); }
__device__ __forceinline__ unsigned long long packFC(float C, unsigned fbits) {
  return ((unsigned long long)__builtin_bit_cast(unsigned, C) << 32) | fbits;
}

// ---------------- f32 -> f16 bulk convert (8 elems/thread) ----------------
__global__ __launch_bounds__(256) void cvt_f32_to_f16(const float* __restrict__ in,
                                                      unsigned short* __restrict__ out) {
  size_t i = ((size_t)blockIdx.x * 256 + threadIdx.x) * 8;
  float4 a = *(const float4*)(in + i);
  float4 b = *(const float4*)(in + i + 4);
  u16x8 r;
  r[0] = f2h(a.x); r[1] = f2h(a.y); r[2] = f2h(a.z); r[3] = f2h(a.w);
  r[4] = f2h(b.x); r[5] = f2h(b.y); r[6] = f2h(b.z); r[7] = f2h(b.w);
  *(u16x8*)(out + i) = r;
}

// ---------------- f16 MFMA GEMM: 3-buffer ring, counted vmcnt(4) (71us proven) ----------------
// C[m][n] = sum_k A[m][k] * B[n][k]. A:[M][512], B:[1536][512] (B^T), C:[M][1536] f16.
__global__ __launch_bounds__(256) void gemm_mfma(const unsigned short* __restrict__ A,
                                                 const unsigned short* __restrict__ B,
                                                 unsigned short* __restrict__ C) {
  __shared__ unsigned short lds[3][8192];
  const int tid = threadIdx.x;
  const int nwg = (M_ROWS / 128) * (N3H / 128);      // 3072
  const int cpx = nwg / 8;                           // 384 (bijective: 3072 % 8 == 0)
  const int swz = (blockIdx.x % 8) * cpx + blockIdx.x / 8;
  const int bm = swz / (N3H / 128);
  const int bn = swz % (N3H / 128);
  const int lane = tid & 63;
  const int wid = tid >> 6;
  const int wm = (wid >> 1) * 64, wn = (wid & 1) * 64;

  const unsigned short* Ag = A + (size_t)bm * 128 * GK;
  const unsigned short* Bg = B + (size_t)bn * 128 * GK;

  const int s0 = tid, s1 = tid + 256;
  const int r0 = s0 >> 2, c0 = (s0 & 3) * 8;
  const int r1 = s1 >> 2, c1 = (s1 & 3) * 8;

  const int fr = lane & 15;         // fragment row (M for A, N for B)
  const int ko = (lane >> 4) * 8;   // fragment k offset (8 contiguous)

  f32x4 acc[4][4];
#pragma unroll
  for (int i = 0; i < 4; ++i)
#pragma unroll
    for (int j = 0; j < 4; ++j) acc[i][j] = (f32x4){0.f, 0.f, 0.f, 0.f};

#define STAGE(buf, k0)                                                                              \
  {                                                                                                 \
    __builtin_amdgcn_global_load_lds(                                                               \
        (const __attribute__((address_space(1))) void*)(Ag + (size_t)r0 * GK + (k0) + c0),          \
        (__attribute__((address_space(3))) void*)&lds[buf][s0 * 8], 16, 0, 0);                      \
    __builtin_amdgcn_global_load_lds(                                                               \
        (const __attribute__((address_space(1))) void*)(Ag + (size_t)r1 * GK + (k0) + c1),          \
        (__attribute__((address_space(3))) void*)&lds[buf][s1 * 8], 16, 0, 0);                      \
    __builtin_amdgcn_global_load_lds(                                                               \
        (const __attribute__((address_space(1))) void*)(Bg + (size_t)r0 * GK + (k0) + c0),          \
        (__attribute__((address_space(3))) void*)&lds[buf][4096 + s0 * 8], 16, 0, 0);               \
    __builtin_amdgcn_global_load_lds(                                                               \
        (const __attribute__((address_space(1))) void*)(Bg + (size_t)r1 * GK + (k0) + c1),          \
        (__attribute__((address_space(3))) void*)&lds[buf][4096 + s1 * 8], 16, 0, 0);               \
  }

  STAGE(0, 0);
  STAGE(1, 32);
#pragma unroll 1
  for (int kt = 0; kt < 16; ++kt) {
    if (kt < 15) {
      asm volatile("s_waitcnt vmcnt(4)" ::: "memory");
    } else {
      asm volatile("s_waitcnt vmcnt(0)" ::: "memory");
    }
    __builtin_amdgcn_s_barrier();
    __builtin_amdgcn_sched_barrier(0);   // pin: nothing moves above the barrier
    if (kt + 2 < 16) STAGE((kt + 2) % 3, (kt + 2) * 32);
    const int cb = kt % 3;
    f16x8 af[4], bfr[4];
#pragma unroll
    for (int t = 0; t < 4; ++t) {
      af[t]  = *(const f16x8*)&lds[cb][(wm + t * 16 + fr) * 32 + ko];
      bfr[t] = *(const f16x8*)&lds[cb][4096 + (wn + t * 16 + fr) * 32 + ko];
    }
#pragma unroll
    for (int mt = 0; mt < 4; ++mt)
#pragma unroll
      for (int nt = 0; nt < 4; ++nt)
        acc[mt][nt] = __builtin_amdgcn_mfma_f32_16x16x32_f16(af[mt], bfr[nt], acc[mt][nt], 0, 0, 0);
  }
#undef STAGE

  // ---- coalesced C-write via LDS transpose (row stride padded to 136) ----
  __syncthreads();  // all waves done reading buffers
  unsigned short* cl = &lds[0][0];
  const int er = (lane >> 4) * 4;   // C/D layout: col=lane&15, row=(lane>>4)*4+reg
#pragma unroll
  for (int mt = 0; mt < 4; ++mt)
#pragma unroll
    for (int nt = 0; nt < 4; ++nt) {
      const int row = wm + mt * 16 + er;
      const int col = wn + nt * 16 + fr;
#pragma unroll
      for (int j = 0; j < 4; ++j) cl[(row + j) * 136 + col] = f2h(acc[mt][nt][j]);
    }
  __syncthreads();
  unsigned short* Cb = C + (size_t)bm * 128 * N3H + bn * 128;
#pragma unroll
  for (int i = 0; i < 8; ++i) {
    int flat = i * 2048 + tid * 8;
    int r = flat >> 7, c = flat & 127;
    *(u16x8*)(Cb + (size_t)r * N3H + c) = *(const u16x8*)&cl[r * 136 + c];
  }
}

// ---------------- Fused single-pass SRU scan: decoupled lookback + PREFIX ----------------
// Grid: 64 segments x 16 batch = 1024 blocks; 256 thr x 2h = 512 chains/block.
// Protocol (rocPRIM-style, single 64-bit word per (seg, chain), pre-zeroed):
//   aggregate:  (C_agg  | -F_agg)   F_agg in [0,1] -> low-word in (-1,-0], sign=published
//   prefix:     (C_pref | -2.0f)    published AND subsumes all predecessors
// Publish aggregate first (publish-before-wait => deadlock-free); walk back
// reading words: prefix -> terminate; aggregate -> accumulate and continue
// (P<1e-5 fallback exit). Then OVERWRITE own slot with the inclusive prefix
// c_end = F_local*ci + C_local, collapsing followers' walks to ~2-4 steps.
// Segment 0 publishes its prefix immediately.
__global__ __launch_bounds__(256, 4) void sru_scan_fused(
    const unsigned short* __restrict__ U,     // [L][B][3H] f16: xt | zf | zr
    const float* __restrict__ bias,           // [2H]
    unsigned long long* __restrict__ FC,      // [NSEG][B][H] packed, pre-zeroed
    unsigned short* hb) {                     // [L][B][H] f16, updated in place
  const int s = blockIdx.x >> 4;
  const int b = blockIdx.x & 15;
  const int h0 = threadIdx.x << 1;
  const float bf0 = bias[h0], bf1 = bias[h0 + 1];
  const float br0 = bias[HID + h0], br1 = bias[HID + h0 + 1];

  const size_t rowstep = (size_t)BATCH * N3H;
  const unsigned short* Up = U + ((size_t)(s * CHUNK) * BATCH + b) * N3H + h0;

  // ---- phase 1: local (F, C | c0=0); retain packed (f16 f, f16 xt) per step
  unsigned fx0[CHUNK], fx1[CHUNK];
  float F0 = 1.f, F1 = 1.f, c0 = 0.f, c1 = 0.f;
#pragma unroll
  for (int i = 0; i < CHUNK; ++i) {
    const unsigned short* p = Up + (size_t)i * rowstep;
    unsigned xt = *(const unsigned*)(p);
    unsigned zf = *(const unsigned*)(p + HID);
    unsigned short fh0 = f2h(sigm(h2f((unsigned short)zf) + bf0));
    unsigned short fh1 = f2h(sigm(h2f((unsigned short)(zf >> 16)) + bf1));
    float f0 = h2f(fh0), f1 = h2f(fh1);
    c0 = f0 * c0 + (1.f - f0) * h2f((unsigned short)xt);
    c1 = f1 * c1 + (1.f - f1) * h2f((unsigned short)(xt >> 16));
    F0 *= f0; F1 *= f1;
    fx0[i] = (xt & 0xffffu) | ((unsigned)fh0 << 16);
    fx1[i] = (xt >> 16) | ((unsigned)fh1 << 16);
  }

  // ---- publish: seg 0 -> prefix (its aggregate IS the prefix); else aggregate
  const size_t ch = ((size_t)s * BATCH + b) * HID + h0;
  if (s == 0) {
    atomicExch(&FC[ch], packFC(c0, PREFIX_TAG));
    atomicExch(&FC[ch + 1], packFC(c1, PREFIX_TAG));
  } else {
    atomicExch(&FC[ch], packFC(c0, __builtin_bit_cast(unsigned, -F0)));
    atomicExch(&FC[ch + 1], packFC(c1, __builtin_bit_cast(unsigned, -F1)));
  }

  // ---- lookback with prefix termination
  float ci0 = 0.f, ci1 = 0.f, P0 = 1.f, P1 = 1.f;
  bool done0 = (s == 0), done1 = (s == 0);
  for (int j = s - 1; j >= 0 && !(done0 && done1); --j) {
    const size_t cj = ((size_t)j * BATCH + b) * HID + h0;
    if (!done0) {
      unsigned long long v;
      do { v = atomicAdd(&FC[cj], 0ULL); } while (!(v & 0x80000000ULL));
      unsigned fb = (unsigned)v;
      float Cv = __builtin_bit_cast(float, (unsigned)(v >> 32));
      if (fb == PREFIX_TAG) { ci0 += P0 * Cv; done0 = true; }
      else {
        ci0 += P0 * Cv;
        P0 *= -__builtin_bit_cast(float, fb);
        if (P0 < 1e-5f) done0 = true;
      }
    }
    if (!done1) {
      unsigned long long v;
      do { v = atomicAdd(&FC[cj + 1], 0ULL); } while (!(v & 0x80000000ULL));
      unsigned fb = (unsigned)v;
      float Cv = __builtin_bit_cast(float, (unsigned)(v >> 32));
      if (fb == PREFIX_TAG) { ci1 += P1 * Cv; done1 = true; }
      else {
        ci1 += P1 * Cv;
        P1 *= -__builtin_bit_cast(float, fb);
        if (P1 < 1e-5f) done1 = true;
      }
    }
  }

  // ---- publish inclusive prefix (overwrite own slot) -> followers terminate fast
  if (s > 0) {
    atomicExch(&FC[ch], packFC(F0 * ci0 + c0, PREFIX_TAG));
    atomicExch(&FC[ch + 1], packFC(F1 * ci1 + c1, PREFIX_TAG));
  }

  // ---- phase 3: replay with carry; read zr + x, write h in place
  float cc0 = ci0, cc1 = ci1;
  const size_t hstep = (size_t)BATCH * HID;
  unsigned short* hp = hb + ((size_t)(s * CHUNK) * BATCH + b) * HID + h0;
#pragma unroll
  for (int i = 0; i < CHUNK; ++i) {
    unsigned zr = *(const unsigned*)(Up + (size_t)i * rowstep + 2 * HID);
    unsigned xv = *(const unsigned*)(hp + (size_t)i * hstep);
    float f0 = h2f((unsigned short)(fx0[i] >> 16));
    float f1 = h2f((unsigned short)(fx1[i] >> 16));
    cc0 = f0 * cc0 + (1.f - f0) * h2f((unsigned short)fx0[i]);
    cc1 = f1 * cc1 + (1.f - f1) * h2f((unsigned short)fx1[i]);
    float r0 = sigm(h2f((unsigned short)zr) + br0);
    float r1 = sigm(h2f((unsigned short)(zr >> 16)) + br1);
    float hn0 = r0 * cc0 + (1.f - r0) * h2f((unsigned short)xv);
    float hn1 = r1 * cc1 + (1.f - r1) * h2f((unsigned short)(xv >> 16));
    *(unsigned*)(hp + (size_t)i * hstep) = (unsigned)f2h(hn0) | ((unsigned)f2h(hn1) << 16);
  }
}

// ---------------- FC head (f16 H, f32 math) ----------------
#define FCR 16
__global__ __launch_bounds__(256) void fc_kernel(const unsigned short* __restrict__ H,
                                                 const float* __restrict__ W,
                                                 const float* __restrict__ bv,
                                                 float* __restrict__ out) {
  __shared__ float hs[FCR][516];
  __shared__ float ws[OUT_DIM][516];
  const int tid = threadIdx.x;
  const size_t m0 = (size_t)blockIdx.x * FCR;
#pragma unroll
  for (int i = 0; i < 4; ++i) {
    int f = tid + i * 256;
    int row = f >> 6;     // 0..15
    int kq = f & 63;      // 8-elem group
    u16x8 v = *(const u16x8*)(H + (m0 + row) * 512 + kq * 8);
#pragma unroll
    for (int j = 0; j < 8; ++j) hs[row][kq * 8 + j] = h2f(v[j]);
  }
#pragma unroll
  for (int i = 0; i < 5; ++i) {
    int f = tid + i * 256;
    int row = f >> 7;     // 0..9
    int kq = f & 127;
    float4 v = *(const float4*)(W + row * 512 + kq * 4);
    *(float4*)&ws[row][kq * 4] = v;
  }
  __syncthreads();
  if (tid < FCR * OUT_DIM) {
    int row = tid / OUT_DIM;
    int o = tid - row * OUT_DIM;
    float acc = bv[o];
#pragma unroll 8
    for (int k = 0; k < 512; ++k) acc += hs[row][k] * ws[o][k];
    out[(m0 + row) * OUT_DIM + o] = acc;
  }
}

extern "C" void kernel_launch(void* const* d_in, const int* in_sizes, int n_in,
                              void* d_out, int out_size, void* d_ws, size_t ws_size,
                              hipStream_t stream) {
  const float* x   = (const float*)d_in[0];  // [2048][16][512]
  const float* Ws  = (const float*)d_in[1];  // [5][1536][512]
  const float* bs  = (const float*)d_in[2];  // [5][1024]
  const float* fcW = (const float*)d_in[3];  // [10][512]
  const float* fcb = (const float*)d_in[4];  // [10]
  float* out = (float*)d_out;

  char* ws = (char*)d_ws;
  const size_t MiB = 1024 * 1024;
  unsigned short* Ub = (unsigned short*)ws;                  // 96 MiB: [M][1536] f16
  unsigned short* hb = (unsigned short*)(ws + 96 * MiB);     // 32 MiB: [M][512] f16
  unsigned short* Wh = (unsigned short*)(ws + 128 * MiB);    // 7.5 MiB f16 weights
  unsigned long long* FC = (unsigned long long*)(ws + 136 * MiB);  // 20 MiB: 5 epochs
  // total 156 MiB <= 256 MiB workspace

  // one-time converts + single lookback-buffer clear for ALL layers
  hipMemsetAsync(FC, 0, (size_t)NLAYERS * NSEG * BATCH * HID * 8, stream);
  cvt_f32_to_f16<<<(NLAYERS * N3H * HID) / (256 * 8), 256, 0, stream>>>(Ws, Wh);
  cvt_f32_to_f16<<<(M_ROWS * HID) / (256 * 8), 256, 0, stream>>>(x, hb);

  for (int l = 0; l < NLAYERS; ++l) {
    gemm_mfma<<<(M_ROWS / 128) * (N3H / 128), 256, 0, stream>>>(
        hb, Wh + (size_t)l * N3H * HID, Ub);
    sru_scan_fused<<<NSEG * BATCH, 256, 0, stream>>>(
        Ub, bs + (size_t)l * 2 * HID,
        FC + (size_t)l * NSEG * BATCH * HID, hb);
  }
  fc_kernel<<<M_ROWS / FCR, 256, 0, stream>>>(hb, fcW, fcb, out);
}

// Round 16
// 627.062 us; speedup vs baseline: 1.1223x; 1.0053x over previous
//
#include <hip/hip_runtime.h>
#include <hip/hip_bf16.h>

#define SEQ 2048
#define BATCH 16
#define HID 512
#define OUT_DIM 10
#define NLAYERS 5
#define M_ROWS (SEQ * BATCH)   // 32768
#define N3H (3 * HID)          // 1536
#define GK HID                 // GEMM K

#define CHUNK 32
#define NSEG (SEQ / CHUNK)     // 64

typedef __attribute__((ext_vector_type(8))) _Float16 f16x8;
typedef __attribute__((ext_vector_type(4))) float f32x4;
typedef __attribute__((ext_vector_type(8))) unsigned short u16x8;

__device__ __forceinline__ unsigned short f2h(float x) {
  return __builtin_bit_cast(unsigned short, (_Float16)x);
}
__device__ __forceinline__ float h2f(unsigned short v) {
  return (float)__builtin_bit_cast(_Float16, v);
}
__device__ __forceinline__ float sigm(float x) { return 1.f / (1.f + __expf(-x)); }

// ---------------- f32 -> f16 bulk convert (8 elems/thread) ----------------
__global__ __launch_bounds__(256) void cvt_f32_to_f16(const float* __restrict__ in,
                                                      unsigned short* __restrict__ out) {
  size_t i = ((size_t)blockIdx.x * 256 + threadIdx.x) * 8;
  float4 a = *(const float4*)(in + i);
  float4 b = *(const float4*)(in + i + 4);
  u16x8 r;
  r[0] = f2h(a.x); r[1] = f2h(a.y); r[2] = f2h(a.z); r[3] = f2h(a.w);
  r[4] = f2h(b.x); r[5] = f2h(b.y); r[6] = f2h(b.z); r[7] = f2h(b.w);
  *(u16x8*)(out + i) = r;
}

// ---------------- f16 MFMA GEMM: 3-buffer ring, counted vmcnt(4) (71us proven) ----------------
// C[m][n] = sum_k A[m][k] * B[n][k]. A:[M][512], B:[1536][512] (B^T), C:[M][1536] f16.
__global__ __launch_bounds__(256) void gemm_mfma(const unsigned short* __restrict__ A,
                                                 const unsigned short* __restrict__ B,
                                                 unsigned short* __restrict__ C) {
  __shared__ unsigned short lds[3][8192];
  const int tid = threadIdx.x;
  const int nwg = (M_ROWS / 128) * (N3H / 128);      // 3072
  const int cpx = nwg / 8;                           // 384 (bijective: 3072 % 8 == 0)
  const int swz = (blockIdx.x % 8) * cpx + blockIdx.x / 8;
  const int bm = swz / (N3H / 128);
  const int bn = swz % (N3H / 128);
  const int lane = tid & 63;
  const int wid = tid >> 6;
  const int wm = (wid >> 1) * 64, wn = (wid & 1) * 64;

  const unsigned short* Ag = A + (size_t)bm * 128 * GK;
  const unsigned short* Bg = B + (size_t)bn * 128 * GK;

  const int s0 = tid, s1 = tid + 256;
  const int r0 = s0 >> 2, c0 = (s0 & 3) * 8;
  const int r1 = s1 >> 2, c1 = (s1 & 3) * 8;

  const int fr = lane & 15;         // fragment row (M for A, N for B)
  const int ko = (lane >> 4) * 8;   // fragment k offset (8 contiguous)

  f32x4 acc[4][4];
#pragma unroll
  for (int i = 0; i < 4; ++i)
#pragma unroll
    for (int j = 0; j < 4; ++j) acc[i][j] = (f32x4){0.f, 0.f, 0.f, 0.f};

#define STAGE(buf, k0)                                                                              \
  {                                                                                                 \
    __builtin_amdgcn_global_load_lds(                                                               \
        (const __attribute__((address_space(1))) void*)(Ag + (size_t)r0 * GK + (k0) + c0),          \
        (__attribute__((address_space(3))) void*)&lds[buf][s0 * 8], 16, 0, 0);                      \
    __builtin_amdgcn_global_load_lds(                                                               \
        (const __attribute__((address_space(1))) void*)(Ag + (size_t)r1 * GK + (k0) + c1),          \
        (__attribute__((address_space(3))) void*)&lds[buf][s1 * 8], 16, 0, 0);                      \
    __builtin_amdgcn_global_load_lds(                                                               \
        (const __attribute__((address_space(1))) void*)(Bg + (size_t)r0 * GK + (k0) + c0),          \
        (__attribute__((address_space(3))) void*)&lds[buf][4096 + s0 * 8], 16, 0, 0);               \
    __builtin_amdgcn_global_load_lds(                                                               \
        (const __attribute__((address_space(1))) void*)(Bg + (size_t)r1 * GK + (k0) + c1),          \
        (__attribute__((address_space(3))) void*)&lds[buf][4096 + s1 * 8], 16, 0, 0);               \
  }

  STAGE(0, 0);
  STAGE(1, 32);
#pragma unroll 1
  for (int kt = 0; kt < 16; ++kt) {
    if (kt < 15) {
      asm volatile("s_waitcnt vmcnt(4)" ::: "memory");
    } else {
      asm volatile("s_waitcnt vmcnt(0)" ::: "memory");
    }
    __builtin_amdgcn_s_barrier();
    __builtin_amdgcn_sched_barrier(0);   // pin: nothing moves above the barrier
    if (kt + 2 < 16) STAGE((kt + 2) % 3, (kt + 2) * 32);
    const int cb = kt % 3;
    f16x8 af[4], bfr[4];
#pragma unroll
    for (int t = 0; t < 4; ++t) {
      af[t]  = *(const f16x8*)&lds[cb][(wm + t * 16 + fr) * 32 + ko];
      bfr[t] = *(const f16x8*)&lds[cb][4096 + (wn + t * 16 + fr) * 32 + ko];
    }
#pragma unroll
    for (int mt = 0; mt < 4; ++mt)
#pragma unroll
      for (int nt = 0; nt < 4; ++nt)
        acc[mt][nt] = __builtin_amdgcn_mfma_f32_16x16x32_f16(af[mt], bfr[nt], acc[mt][nt], 0, 0, 0);
  }
#undef STAGE

  // ---- coalesced C-write via LDS transpose (row stride padded to 136) ----
  __syncthreads();  // all waves done reading buffers
  unsigned short* cl = &lds[0][0];
  const int er = (lane >> 4) * 4;   // C/D layout: col=lane&15, row=(lane>>4)*4+reg
#pragma unroll
  for (int mt = 0; mt < 4; ++mt)
#pragma unroll
    for (int nt = 0; nt < 4; ++nt) {
      const int row = wm + mt * 16 + er;
      const int col = wn + nt * 16 + fr;
#pragma unroll
      for (int j = 0; j < 4; ++j) cl[(row + j) * 136 + col] = f2h(acc[mt][nt][j]);
    }
  __syncthreads();
  unsigned short* Cb = C + (size_t)bm * 128 * N3H + bn * 128;
#pragma unroll
  for (int i = 0; i < 8; ++i) {
    int flat = i * 2048 + tid * 8;
    int r = flat >> 7, c = flat & 127;
    *(u16x8*)(Cb + (size_t)r * N3H + c) = *(const u16x8*)&cl[r * 136 + c];
  }
}

// ---------------- Fused single-pass SRU scan (decoupled lookback; R12 proven) ----------------
// Grid: 64 segments x 16 batch = 1024 blocks; 256 thr x 2h = 512 chains/block.
// Publish (F, C) packed in ONE 64-bit word via atomicExch; F stored NEGATED so
// the low word's sign bit doubles as the "published" tag. FC pre-zeroed (one
// memset covers all 5 layer epochs). Lookback early-exit at P < 1e-5.
__global__ __launch_bounds__(256, 4) void sru_scan_fused(
    const unsigned short* __restrict__ U,     // [L][B][3H] f16: xt | zf | zr
    const float* __restrict__ bias,           // [2H]
    unsigned long long* __restrict__ FC,      // [NSEG][B][H] packed, pre-zeroed
    unsigned short* hb) {                     // [L][B][H] f16, updated in place
  const int s = blockIdx.x >> 4;
  const int b = blockIdx.x & 15;
  const int h0 = threadIdx.x << 1;
  const float bf0 = bias[h0], bf1 = bias[h0 + 1];
  const float br0 = bias[HID + h0], br1 = bias[HID + h0 + 1];

  const size_t rowstep = (size_t)BATCH * N3H;
  const unsigned short* Up = U + ((size_t)(s * CHUNK) * BATCH + b) * N3H + h0;

  // ---- phase 1: local (F, C | c0=0); retain packed (f16 f, f16 xt) per step
  unsigned fx0[CHUNK], fx1[CHUNK];
  float F0 = 1.f, F1 = 1.f, c0 = 0.f, c1 = 0.f;
#pragma unroll
  for (int i = 0; i < CHUNK; ++i) {
    const unsigned short* p = Up + (size_t)i * rowstep;
    unsigned xt = *(const unsigned*)(p);
    unsigned zf = *(const unsigned*)(p + HID);
    unsigned short fh0 = f2h(sigm(h2f((unsigned short)zf) + bf0));
    unsigned short fh1 = f2h(sigm(h2f((unsigned short)(zf >> 16)) + bf1));
    float f0 = h2f(fh0), f1 = h2f(fh1);
    c0 = f0 * c0 + (1.f - f0) * h2f((unsigned short)xt);
    c1 = f1 * c1 + (1.f - f1) * h2f((unsigned short)(xt >> 16));
    F0 *= f0; F1 *= f1;
    fx0[i] = (xt & 0xffffu) | ((unsigned)fh0 << 16);
    fx1[i] = (xt >> 16) | ((unsigned)fh1 << 16);
  }

  // ---- publish (single-word atomic; no fence needed)
  const size_t ch = ((size_t)s * BATCH + b) * HID + h0;
  atomicExch(&FC[ch],
             ((unsigned long long)__builtin_bit_cast(unsigned, c0) << 32) |
                 __builtin_bit_cast(unsigned, -F0));
  atomicExch(&FC[ch + 1],
             ((unsigned long long)__builtin_bit_cast(unsigned, c1) << 32) |
                 __builtin_bit_cast(unsigned, -F1));

  // ---- lookback: c_in = sum_{j<s} C_j * prod_{j<k<s} F_k
  float ci0 = 0.f, ci1 = 0.f, P0 = 1.f, P1 = 1.f;
  for (int j = s - 1; j >= 0; --j) {
    const size_t cj = ((size_t)j * BATCH + b) * HID + h0;
    unsigned long long v0, v1;
    do { v0 = atomicAdd(&FC[cj], 0ULL); } while (!(v0 & 0x80000000ULL));
    do { v1 = atomicAdd(&FC[cj + 1], 0ULL); } while (!(v1 & 0x80000000ULL));
    float Fj0 = -__builtin_bit_cast(float, (unsigned)v0);
    float Cj0 = __builtin_bit_cast(float, (unsigned)(v0 >> 32));
    float Fj1 = -__builtin_bit_cast(float, (unsigned)v1);
    float Cj1 = __builtin_bit_cast(float, (unsigned)(v1 >> 32));
    ci0 += P0 * Cj0; P0 *= Fj0;
    ci1 += P1 * Cj1; P1 *= Fj1;
    if (P0 < 1e-5f && P1 < 1e-5f) break;   // remaining contribution < f16 ulp
  }

  // ---- phase 3: replay with carry; read zr + x, write h in place
  float cc0 = ci0, cc1 = ci1;
  const size_t hstep = (size_t)BATCH * HID;
  unsigned short* hp = hb + ((size_t)(s * CHUNK) * BATCH + b) * HID + h0;
#pragma unroll
  for (int i = 0; i < CHUNK; ++i) {
    unsigned zr = *(const unsigned*)(Up + (size_t)i * rowstep + 2 * HID);
    unsigned xv = *(const unsigned*)(hp + (size_t)i * hstep);
    float f0 = h2f((unsigned short)(fx0[i] >> 16));
    float f1 = h2f((unsigned short)(fx1[i] >> 16));
    cc0 = f0 * cc0 + (1.f - f0) * h2f((unsigned short)fx0[i]);
    cc1 = f1 * cc1 + (1.f - f1) * h2f((unsigned short)fx1[i]);
    float r0 = sigm(h2f((unsigned short)zr) + br0);
    float r1 = sigm(h2f((unsigned short)(zr >> 16)) + br1);
    float hn0 = r0 * cc0 + (1.f - r0) * h2f((unsigned short)xv);
    float hn1 = r1 * cc1 + (1.f - r1) * h2f((unsigned short)(xv >> 16));
    *(unsigned*)(hp + (size_t)i * hstep) = (unsigned)f2h(hn0) | ((unsigned)f2h(hn1) << 16);
  }
}

// ---------------- FC head: wave-per-row, W in registers, shuffle-reduce ----------------
// out[m][o] = sum_k H[m][k]*W[o][k] + b[o]. H f16 (L3-hot), W f32 10x512.
// Each lane holds W[o][lane*8 .. lane*8+7] for all 10 o (80 VGPR, loaded once).
// Per row: one coalesced u16x8 H-load (1 KB/wave), 80 FMA, 10 butterfly
// reductions; lanes 0..9 store the 10 outputs. 1024 waves x 32 rows.
__global__ __launch_bounds__(256) void fc_wave(const unsigned short* __restrict__ H,
                                               const float* __restrict__ W,
                                               const float* __restrict__ bv,
                                               float* __restrict__ out) {
  const int lane = threadIdx.x & 63;
  const int wave = blockIdx.x * 4 + (threadIdx.x >> 6);   // 0..1023
  const int k0 = lane * 8;

  float wreg[OUT_DIM][8];
#pragma unroll
  for (int o = 0; o < OUT_DIM; ++o) {
    float4 a = *(const float4*)(W + o * HID + k0);
    float4 b = *(const float4*)(W + o * HID + k0 + 4);
    wreg[o][0] = a.x; wreg[o][1] = a.y; wreg[o][2] = a.z; wreg[o][3] = a.w;
    wreg[o][4] = b.x; wreg[o][5] = b.y; wreg[o][6] = b.z; wreg[o][7] = b.w;
  }
  const float bo = (lane < OUT_DIM) ? bv[lane] : 0.f;

  const size_t row0 = (size_t)wave * 32;
#pragma unroll 1
  for (int i = 0; i < 32; ++i) {
    const size_t row = row0 + i;
    u16x8 hv8 = *(const u16x8*)(H + row * HID + k0);
    float hv[8];
#pragma unroll
    for (int j = 0; j < 8; ++j) hv[j] = h2f(hv8[j]);
    float vout = 0.f;
#pragma unroll
    for (int o = 0; o < OUT_DIM; ++o) {
      float p = 0.f;
#pragma unroll
      for (int j = 0; j < 8; ++j) p += hv[j] * wreg[o][j];
#pragma unroll
      for (int m = 32; m > 0; m >>= 1) p += __shfl_xor(p, m);
      if (lane == o) vout = p;
    }
    if (lane < OUT_DIM) out[row * OUT_DIM + lane] = vout + bo;
  }
}

extern "C" void kernel_launch(void* const* d_in, const int* in_sizes, int n_in,
                              void* d_out, int out_size, void* d_ws, size_t ws_size,
                              hipStream_t stream) {
  const float* x   = (const float*)d_in[0];  // [2048][16][512]
  const float* Ws  = (const float*)d_in[1];  // [5][1536][512]
  const float* bs  = (const float*)d_in[2];  // [5][1024]
  const float* fcW = (const float*)d_in[3];  // [10][512]
  const float* fcb = (const float*)d_in[4];  // [10]
  float* out = (float*)d_out;

  char* ws = (char*)d_ws;
  const size_t MiB = 1024 * 1024;
  unsigned short* Ub = (unsigned short*)ws;                  // 96 MiB: [M][1536] f16
  unsigned short* hb = (unsigned short*)(ws + 96 * MiB);     // 32 MiB: [M][512] f16
  unsigned short* Wh = (unsigned short*)(ws + 128 * MiB);    // 7.5 MiB f16 weights
  unsigned long long* FC = (unsigned long long*)(ws + 136 * MiB);  // 20 MiB: 5 epochs
  // total 156 MiB <= 256 MiB workspace

  // one-time converts + single lookback-buffer clear for ALL layers
  hipMemsetAsync(FC, 0, (size_t)NLAYERS * NSEG * BATCH * HID * 8, stream);
  cvt_f32_to_f16<<<(NLAYERS * N3H * HID) / (256 * 8), 256, 0, stream>>>(Ws, Wh);
  cvt_f32_to_f16<<<(M_ROWS * HID) / (256 * 8), 256, 0, stream>>>(x, hb);

  for (int l = 0; l < NLAYERS; ++l) {
    gemm_mfma<<<(M_ROWS / 128) * (N3H / 128), 256, 0, stream>>>(
        hb, Wh + (size_t)l * N3H * HID, Ub);
    sru_scan_fused<<<NSEG * BATCH, 256, 0, stream>>>(
        Ub, bs + (size_t)l * 2 * HID,
        FC + (size_t)l * NSEG * BATCH * HID, hb);
  }
  fc_wave<<<256, 256, 0, stream>>>(hb, fcW, fcb, out);
}

// Round 17
// 614.014 us; speedup vs baseline: 1.1461x; 1.0213x over previous
//
#include <hip/hip_runtime.h>
#include <hip/hip_bf16.h>

#define SEQ 2048
#define BATCH 16
#define HID 512
#define OUT_DIM 10
#define NLAYERS 5
#define M_ROWS (SEQ * BATCH)   // 32768
#define N3H (3 * HID)          // 1536
#define GK HID                 // GEMM K

#define CHUNK 32
#define NSEG (SEQ / CHUNK)     // 64

typedef __attribute__((ext_vector_type(8))) _Float16 f16x8;
typedef __attribute__((ext_vector_type(4))) float f32x4;
typedef __attribute__((ext_vector_type(8))) unsigned short u16x8;

__device__ __forceinline__ unsigned short f2h(float x) {
  return __builtin_bit_cast(unsigned short, (_Float16)x);
}
__device__ __forceinline__ float h2f(unsigned short v) {
  return (float)__builtin_bit_cast(_Float16, v);
}
__device__ __forceinline__ float sigm(float x) { return 1.f / (1.f + __expf(-x)); }

// ---------------- f32 -> f16 bulk convert (8 elems/thread) ----------------
__global__ __launch_bounds__(256) void cvt_f32_to_f16(const float* __restrict__ in,
                                                      unsigned short* __restrict__ out) {
  size_t i = ((size_t)blockIdx.x * 256 + threadIdx.x) * 8;
  float4 a = *(const float4*)(in + i);
  float4 b = *(const float4*)(in + i + 4);
  u16x8 r;
  r[0] = f2h(a.x); r[1] = f2h(a.y); r[2] = f2h(a.z); r[3] = f2h(a.w);
  r[4] = f2h(b.x); r[5] = f2h(b.y); r[6] = f2h(b.z); r[7] = f2h(b.w);
  *(u16x8*)(out + i) = r;
}

// ---------------- f16 MFMA GEMM: 3-buffer ring, counted vmcnt(4) (71us proven) ----------------
// C[m][n] = sum_k A[m][k] * B[n][k]. A:[M][512], B:[1536][512] (B^T), C:[M][1536] f16.
__global__ __launch_bounds__(256) void gemm_mfma(const unsigned short* __restrict__ A,
                                                 const unsigned short* __restrict__ B,
                                                 unsigned short* __restrict__ C) {
  __shared__ unsigned short lds[3][8192];
  const int tid = threadIdx.x;
  const int nwg = (M_ROWS / 128) * (N3H / 128);      // 3072
  const int cpx = nwg / 8;                           // 384 (bijective: 3072 % 8 == 0)
  const int swz = (blockIdx.x % 8) * cpx + blockIdx.x / 8;
  const int bm = swz / (N3H / 128);
  const int bn = swz % (N3H / 128);
  const int lane = tid & 63;
  const int wid = tid >> 6;
  const int wm = (wid >> 1) * 64, wn = (wid & 1) * 64;

  const unsigned short* Ag = A + (size_t)bm * 128 * GK;
  const unsigned short* Bg = B + (size_t)bn * 128 * GK;

  const int s0 = tid, s1 = tid + 256;
  const int r0 = s0 >> 2, c0 = (s0 & 3) * 8;
  const int r1 = s1 >> 2, c1 = (s1 & 3) * 8;

  const int fr = lane & 15;         // fragment row (M for A, N for B)
  const int ko = (lane >> 4) * 8;   // fragment k offset (8 contiguous)

  f32x4 acc[4][4];
#pragma unroll
  for (int i = 0; i < 4; ++i)
#pragma unroll
    for (int j = 0; j < 4; ++j) acc[i][j] = (f32x4){0.f, 0.f, 0.f, 0.f};

#define STAGE(buf, k0)                                                                              \
  {                                                                                                 \
    __builtin_amdgcn_global_load_lds(                                                               \
        (const __attribute__((address_space(1))) void*)(Ag + (size_t)r0 * GK + (k0) + c0),          \
        (__attribute__((address_space(3))) void*)&lds[buf][s0 * 8], 16, 0, 0);                      \
    __builtin_amdgcn_global_load_lds(                                                               \
        (const __attribute__((address_space(1))) void*)(Ag + (size_t)r1 * GK + (k0) + c1),          \
        (__attribute__((address_space(3))) void*)&lds[buf][s1 * 8], 16, 0, 0);                      \
    __builtin_amdgcn_global_load_lds(                                                               \
        (const __attribute__((address_space(1))) void*)(Bg + (size_t)r0 * GK + (k0) + c0),          \
        (__attribute__((address_space(3))) void*)&lds[buf][4096 + s0 * 8], 16, 0, 0);               \
    __builtin_amdgcn_global_load_lds(                                                               \
        (const __attribute__((address_space(1))) void*)(Bg + (size_t)r1 * GK + (k0) + c1),          \
        (__attribute__((address_space(3))) void*)&lds[buf][4096 + s1 * 8], 16, 0, 0);               \
  }

  STAGE(0, 0);
  STAGE(1, 32);
#pragma unroll 1
  for (int kt = 0; kt < 16; ++kt) {
    if (kt < 15) {
      asm volatile("s_waitcnt vmcnt(4)" ::: "memory");
    } else {
      asm volatile("s_waitcnt vmcnt(0)" ::: "memory");
    }
    __builtin_amdgcn_s_barrier();
    __builtin_amdgcn_sched_barrier(0);   // pin: nothing moves above the barrier
    if (kt + 2 < 16) STAGE((kt + 2) % 3, (kt + 2) * 32);
    const int cb = kt % 3;
    f16x8 af[4], bfr[4];
#pragma unroll
    for (int t = 0; t < 4; ++t) {
      af[t]  = *(const f16x8*)&lds[cb][(wm + t * 16 + fr) * 32 + ko];
      bfr[t] = *(const f16x8*)&lds[cb][4096 + (wn + t * 16 + fr) * 32 + ko];
    }
#pragma unroll
    for (int mt = 0; mt < 4; ++mt)
#pragma unroll
      for (int nt = 0; nt < 4; ++nt)
        acc[mt][nt] = __builtin_amdgcn_mfma_f32_16x16x32_f16(af[mt], bfr[nt], acc[mt][nt], 0, 0, 0);
  }
#undef STAGE

  // ---- coalesced C-write via LDS transpose (row stride padded to 136) ----
  __syncthreads();  // all waves done reading buffers
  unsigned short* cl = &lds[0][0];
  const int er = (lane >> 4) * 4;   // C/D layout: col=lane&15, row=(lane>>4)*4+reg
#pragma unroll
  for (int mt = 0; mt < 4; ++mt)
#pragma unroll
    for (int nt = 0; nt < 4; ++nt) {
      const int row = wm + mt * 16 + er;
      const int col = wn + nt * 16 + fr;
#pragma unroll
      for (int j = 0; j < 4; ++j) cl[(row + j) * 136 + col] = f2h(acc[mt][nt][j]);
    }
  __syncthreads();
  unsigned short* Cb = C + (size_t)bm * 128 * N3H + bn * 128;
#pragma unroll
  for (int i = 0; i < 8; ++i) {
    int flat = i * 2048 + tid * 8;
    int r = flat >> 7, c = flat & 127;
    *(u16x8*)(Cb + (size_t)r * N3H + c) = *(const u16x8*)&cl[r * 136 + c];
  }
}

// ---------------- Fused single-pass SRU scan (decoupled lookback; R12 proven) ----------------
// Grid: 64 segments x 16 batch = 1024 blocks; 256 thr x 2h = 512 chains/block.
// Publish (F, C) packed in ONE 64-bit word via atomicExch; F stored NEGATED so
// the low word's sign bit doubles as the "published" tag. FC pre-zeroed (one
// memset covers all 5 layer epochs). Lookback early-exit at P < 1e-5.
__global__ __launch_bounds__(256, 4) void sru_scan_fused(
    const unsigned short* __restrict__ U,     // [L][B][3H] f16: xt | zf | zr
    const float* __restrict__ bias,           // [2H]
    unsigned long long* __restrict__ FC,      // [NSEG][B][H] packed, pre-zeroed
    unsigned short* hb) {                     // [L][B][H] f16, updated in place
  const int s = blockIdx.x >> 4;
  const int b = blockIdx.x & 15;
  const int h0 = threadIdx.x << 1;
  const float bf0 = bias[h0], bf1 = bias[h0 + 1];
  const float br0 = bias[HID + h0], br1 = bias[HID + h0 + 1];

  const size_t rowstep = (size_t)BATCH * N3H;
  const unsigned short* Up = U + ((size_t)(s * CHUNK) * BATCH + b) * N3H + h0;

  // ---- phase 1: local (F, C | c0=0); retain packed (f16 f, f16 xt) per step
  unsigned fx0[CHUNK], fx1[CHUNK];
  float F0 = 1.f, F1 = 1.f, c0 = 0.f, c1 = 0.f;
#pragma unroll
  for (int i = 0; i < CHUNK; ++i) {
    const unsigned short* p = Up + (size_t)i * rowstep;
    unsigned xt = *(const unsigned*)(p);
    unsigned zf = *(const unsigned*)(p + HID);
    unsigned short fh0 = f2h(sigm(h2f((unsigned short)zf) + bf0));
    unsigned short fh1 = f2h(sigm(h2f((unsigned short)(zf >> 16)) + bf1));
    float f0 = h2f(fh0), f1 = h2f(fh1);
    c0 = f0 * c0 + (1.f - f0) * h2f((unsigned short)xt);
    c1 = f1 * c1 + (1.f - f1) * h2f((unsigned short)(xt >> 16));
    F0 *= f0; F1 *= f1;
    fx0[i] = (xt & 0xffffu) | ((unsigned)fh0 << 16);
    fx1[i] = (xt >> 16) | ((unsigned)fh1 << 16);
  }

  // ---- publish (single-word atomic; no fence needed)
  const size_t ch = ((size_t)s * BATCH + b) * HID + h0;
  atomicExch(&FC[ch],
             ((unsigned long long)__builtin_bit_cast(unsigned, c0) << 32) |
                 __builtin_bit_cast(unsigned, -F0));
  atomicExch(&FC[ch + 1],
             ((unsigned long long)__builtin_bit_cast(unsigned, c1) << 32) |
                 __builtin_bit_cast(unsigned, -F1));

  // ---- lookback: c_in = sum_{j<s} C_j * prod_{j<k<s} F_k
  float ci0 = 0.f, ci1 = 0.f, P0 = 1.f, P1 = 1.f;
  for (int j = s - 1; j >= 0; --j) {
    const size_t cj = ((size_t)j * BATCH + b) * HID + h0;
    unsigned long long v0, v1;
    do { v0 = atomicAdd(&FC[cj], 0ULL); } while (!(v0 & 0x80000000ULL));
    do { v1 = atomicAdd(&FC[cj + 1], 0ULL); } while (!(v1 & 0x80000000ULL));
    float Fj0 = -__builtin_bit_cast(float, (unsigned)v0);
    float Cj0 = __builtin_bit_cast(float, (unsigned)(v0 >> 32));
    float Fj1 = -__builtin_bit_cast(float, (unsigned)v1);
    float Cj1 = __builtin_bit_cast(float, (unsigned)(v1 >> 32));
    ci0 += P0 * Cj0; P0 *= Fj0;
    ci1 += P1 * Cj1; P1 *= Fj1;
    if (P0 < 1e-5f && P1 < 1e-5f) break;   // remaining contribution < f16 ulp
  }

  // ---- phase 3: replay with carry; read zr + x, write h in place
  float cc0 = ci0, cc1 = ci1;
  const size_t hstep = (size_t)BATCH * HID;
  unsigned short* hp = hb + ((size_t)(s * CHUNK) * BATCH + b) * HID + h0;
#pragma unroll
  for (int i = 0; i < CHUNK; ++i) {
    unsigned zr = *(const unsigned*)(Up + (size_t)i * rowstep + 2 * HID);
    unsigned xv = *(const unsigned*)(hp + (size_t)i * hstep);
    float f0 = h2f((unsigned short)(fx0[i] >> 16));
    float f1 = h2f((unsigned short)(fx1[i] >> 16));
    cc0 = f0 * cc0 + (1.f - f0) * h2f((unsigned short)fx0[i]);
    cc1 = f1 * cc1 + (1.f - f1) * h2f((unsigned short)fx1[i]);
    float r0 = sigm(h2f((unsigned short)zr) + br0);
    float r1 = sigm(h2f((unsigned short)(zr >> 16)) + br1);
    float hn0 = r0 * cc0 + (1.f - r0) * h2f((unsigned short)xv);
    float hn1 = r1 * cc1 + (1.f - r1) * h2f((unsigned short)(xv >> 16));
    *(unsigned*)(hp + (size_t)i * hstep) = (unsigned)f2h(hn0) | ((unsigned)f2h(hn1) << 16);
  }
}

// ---------------- FC head: wave-per-4-rows, W in registers, shuffle-reduce ----------------
// out[m][o] = sum_k H[m][k]*W[o][k] + b[o]. H f16 (L3-hot), W f32 10x512.
// 2048 blocks x 4 waves = 8192 waves (8/SIMD: full TLP), 4 rows per wave,
// fully unrolled so the 4 independent row loads issue back-to-back (ILP).
// Each lane holds W[o][lane*8..+7] for all 10 o (80 VGPR, loaded once).
__global__ __launch_bounds__(256) void fc_wave(const unsigned short* __restrict__ H,
                                               const float* __restrict__ W,
                                               const float* __restrict__ bv,
                                               float* __restrict__ out) {
  const int lane = threadIdx.x & 63;
  const int wave = blockIdx.x * 4 + (threadIdx.x >> 6);   // 0..8191
  const int k0 = lane * 8;

  float wreg[OUT_DIM][8];
#pragma unroll
  for (int o = 0; o < OUT_DIM; ++o) {
    float4 a = *(const float4*)(W + o * HID + k0);
    float4 b = *(const float4*)(W + o * HID + k0 + 4);
    wreg[o][0] = a.x; wreg[o][1] = a.y; wreg[o][2] = a.z; wreg[o][3] = a.w;
    wreg[o][4] = b.x; wreg[o][5] = b.y; wreg[o][6] = b.z; wreg[o][7] = b.w;
  }
  const float bo = (lane < OUT_DIM) ? bv[lane] : 0.f;

  const size_t row0 = (size_t)wave * 4;
  // issue all 4 row loads first (independent), then reduce
  u16x8 hv8[4];
#pragma unroll
  for (int i = 0; i < 4; ++i)
    hv8[i] = *(const u16x8*)(H + (row0 + i) * HID + k0);

#pragma unroll
  for (int i = 0; i < 4; ++i) {
    float hv[8];
#pragma unroll
    for (int j = 0; j < 8; ++j) hv[j] = h2f(hv8[i][j]);
    float vout = 0.f;
#pragma unroll
    for (int o = 0; o < OUT_DIM; ++o) {
      float p = 0.f;
#pragma unroll
      for (int j = 0; j < 8; ++j) p += hv[j] * wreg[o][j];
#pragma unroll
      for (int m = 32; m > 0; m >>= 1) p += __shfl_xor(p, m);
      if (lane == o) vout = p;
    }
    if (lane < OUT_DIM) out[(row0 + i) * OUT_DIM + lane] = vout + bo;
  }
}

extern "C" void kernel_launch(void* const* d_in, const int* in_sizes, int n_in,
                              void* d_out, int out_size, void* d_ws, size_t ws_size,
                              hipStream_t stream) {
  const float* x   = (const float*)d_in[0];  // [2048][16][512]
  const float* Ws  = (const float*)d_in[1];  // [5][1536][512]
  const float* bs  = (const float*)d_in[2];  // [5][1024]
  const float* fcW = (const float*)d_in[3];  // [10][512]
  const float* fcb = (const float*)d_in[4];  // [10]
  float* out = (float*)d_out;

  char* ws = (char*)d_ws;
  const size_t MiB = 1024 * 1024;
  unsigned short* Ub = (unsigned short*)ws;                  // 96 MiB: [M][1536] f16
  unsigned short* hb = (unsigned short*)(ws + 96 * MiB);     // 32 MiB: [M][512] f16
  unsigned short* Wh = (unsigned short*)(ws + 128 * MiB);    // 7.5 MiB f16 weights
  unsigned long long* FC = (unsigned long long*)(ws + 136 * MiB);  // 20 MiB: 5 epochs
  // total 156 MiB <= 256 MiB workspace

  // one-time converts + single lookback-buffer clear for ALL layers
  hipMemsetAsync(FC, 0, (size_t)NLAYERS * NSEG * BATCH * HID * 8, stream);
  cvt_f32_to_f16<<<(NLAYERS * N3H * HID) / (256 * 8), 256, 0, stream>>>(Ws, Wh);
  cvt_f32_to_f16<<<(M_ROWS * HID) / (256 * 8), 256, 0, stream>>>(x, hb);

  for (int l = 0; l < NLAYERS; ++l) {
    gemm_mfma<<<(M_ROWS / 128) * (N3H / 128), 256, 0, stream>>>(
        hb, Wh + (size_t)l * N3H * HID, Ub);
    sru_scan_fused<<<NSEG * BATCH, 256, 0, stream>>>(
        Ub, bs + (size_t)l * 2 * HID,
        FC + (size_t)l * NSEG * BATCH * HID, hb);
  }
  fc_wave<<<2048, 256, 0, stream>>>(hb, fcW, fcb, out);
}